// Round 1
// baseline (167.090 us; speedup 1.0000x reference)
//
#include <hip/hip_runtime.h>
#include <hip/hip_bf16.h>

typedef short bf16x8 __attribute__((ext_vector_type(8)));
typedef float f32x4  __attribute__((ext_vector_type(4)));

#define D 128

// f32 -> bf16 round-to-nearest-even (finite inputs)
__device__ __forceinline__ short f2bf(float f) {
    unsigned u = __float_as_uint(f);
    u = (u + 0x7fffu + ((u >> 16) & 1u)) >> 16;
    return (short)u;
}

// LDS byte offset for [row][128 bf16], XOR-swizzled to kill the
// stride-256B bank conflict on ds_read_b128 column-slices (G4).
__device__ __forceinline__ int swz(int row, int intra) {
    return (row << 8) + (intra ^ ((row & 7) << 4));
}

__global__ __launch_bounds__(256, 2)
void edge_decoder_kernel(const float* __restrict__ left,
                         const float* __restrict__ right,
                         const int* __restrict__ pairs,
                         const float* __restrict__ W1,
                         const float* __restrict__ b1,
                         const float* __restrict__ W2,
                         const float* __restrict__ b2,
                         float* __restrict__ out, int E)
{
    __shared__ char smem[65536];
    char* const w1t = smem;          // W1^T bf16 [col c][k], swizzled, 32 KB
    char* const xls = smem + 32768;  // x    bf16 [edge][ch], swizzled, 32 KB

    const int tid  = threadIdx.x;
    const int lane = tid & 63;
    const int wid  = tid >> 6;       // wave id 0..3, owns edges [32w,32w+32)
    const int lg   = lane >> 4;      // lanegroup 0..3
    const int lm   = lane & 15;

    // ---- Phase 0: W1^T (bf16, transposed, swizzled) into LDS ----
    #pragma unroll 4
    for (int j = 0; j < 64; ++j) {
        int idx = j * 256 + tid;          // coalesced read of W1[k][c]
        int k = idx >> 7, c = idx & 127;
        *(short*)(w1t + swz(c, k * 2)) = f2bf(W1[idx]);
    }

    // per-lane slices of b1 / W2 (col = ct*16 + lm matches C-frag layout)
    float b1v[8], w2v[8];
    #pragma unroll
    for (int ct = 0; ct < 8; ++ct) {
        b1v[ct] = b1[ct * 16 + lm];
        w2v[ct] = W2[ct * 16 + lm];
    }
    const float b2s = b2[0];

    __syncthreads();                      // W1^T ready

    const int base = blockIdx.x * 128 + wid * 32;

    // index preload: lanes 0-31 hold pairs0[base+t], lanes 32-63 pairs1[base+t]
    int e0 = base + (lane & 31);
    if (e0 >= E) e0 = E - 1;              // clamp (tail block): safe gather
    const int idxv = pairs[(lane >> 5) * E + e0];

    // ---- Phase 1: gather + multiply -> x (bf16) in LDS (wave-private) ----
    #pragma unroll
    for (int j = 0; j < 16; ++j) {
        const int eoff = 2 * j + (lane >> 5);       // 2 edges per iteration
        const int iL = __shfl(idxv, eoff);          // pairs0[base+eoff]
        const int iR = __shfl(idxv, 32 + eoff);     // pairs1[base+eoff]
        const float4 lv = *(const float4*)(left  + iL * D + (lane & 31) * 4);
        const float4 rv = *(const float4*)(right + iR * D + (lane & 31) * 4);
        short4 xb;
        xb.x = f2bf(lv.x * rv.x);
        xb.y = f2bf(lv.y * rv.y);
        xb.z = f2bf(lv.z * rv.z);
        xb.w = f2bf(lv.w * rv.w);
        *(short4*)(xls + swz(wid * 32 + eoff, (lane & 31) * 8)) = xb;
    }

    // ---- Phase 2: MFMA. A and B both use k = (lane>>4)*8 + e; the result
    // is invariant to the HW's internal k permutation since both operands
    // share it (dot products are K-permutation invariant). ----
    bf16x8 afr[2][4];
    #pragma unroll
    for (int mt = 0; mt < 2; ++mt)
        #pragma unroll
        for (int kt = 0; kt < 4; ++kt)
            afr[mt][kt] = *(const bf16x8*)(
                xls + swz(wid * 32 + mt * 16 + lm, kt * 64 + lg * 16));

    f32x4 acc[2][8];
    #pragma unroll
    for (int mt = 0; mt < 2; ++mt)
        #pragma unroll
        for (int ct = 0; ct < 8; ++ct)
            acc[mt][ct] = (f32x4){0.f, 0.f, 0.f, 0.f};

    #pragma unroll
    for (int kt = 0; kt < 4; ++kt)
        #pragma unroll
        for (int ct = 0; ct < 8; ++ct) {
            const bf16x8 bfr = *(const bf16x8*)(
                w1t + swz(ct * 16 + lm, kt * 64 + lg * 16));
            acc[0][ct] = __builtin_amdgcn_mfma_f32_16x16x32_bf16(
                afr[0][kt], bfr, acc[0][ct], 0, 0, 0);
            acc[1][ct] = __builtin_amdgcn_mfma_f32_16x16x32_bf16(
                afr[1][kt], bfr, acc[1][ct], 0, 0, 0);
        }

    // ---- Phase 3: bias + ReLU + dot(W2) + 16-lane reduce + sigmoid ----
    // C-frag layout (HW-measured): col = lane&15, row = (lane>>4)*4 + reg.
    #pragma unroll
    for (int mt = 0; mt < 2; ++mt) {
        float p0 = 0.f, p1 = 0.f, p2 = 0.f, p3 = 0.f;
        #pragma unroll
        for (int ct = 0; ct < 8; ++ct) {
            float h0 = fmaxf(acc[mt][ct][0] + b1v[ct], 0.f);
            float h1 = fmaxf(acc[mt][ct][1] + b1v[ct], 0.f);
            float h2 = fmaxf(acc[mt][ct][2] + b1v[ct], 0.f);
            float h3 = fmaxf(acc[mt][ct][3] + b1v[ct], 0.f);
            p0 = fmaf(h0, w2v[ct], p0);
            p1 = fmaf(h1, w2v[ct], p1);
            p2 = fmaf(h2, w2v[ct], p2);
            p3 = fmaf(h3, w2v[ct], p3);
        }
        #pragma unroll
        for (int s = 1; s < 16; s <<= 1) {
            p0 += __shfl_xor(p0, s);
            p1 += __shfl_xor(p1, s);
            p2 += __shfl_xor(p2, s);
            p3 += __shfl_xor(p3, s);
        }
        if (lm < 4) {
            // static selection (no runtime-indexed register array -> no scratch)
            const float pv = (lm & 2) ? ((lm & 1) ? p3 : p2)
                                      : ((lm & 1) ? p1 : p0);
            const int e = base + mt * 16 + lg * 4 + lm;
            if (e < E) out[e] = 1.f / (1.f + __expf(-(pv + b2s)));
        }
    }
}

extern "C" void kernel_launch(void* const* d_in, const int* in_sizes, int n_in,
                              void* d_out, int out_size, void* d_ws, size_t ws_size,
                              hipStream_t stream) {
    const float* left  = (const float*)d_in[0];
    const float* right = (const float*)d_in[1];
    const int*   pairs = (const int*)d_in[2];
    const float* W1    = (const float*)d_in[3];
    const float* b1    = (const float*)d_in[4];
    const float* W2    = (const float*)d_in[5];
    const float* b2    = (const float*)d_in[6];
    float* out = (float*)d_out;

    const int E = in_sizes[2] / 2;            // pairs is [2][E]
    const int blocks = (E + 127) / 128;       // 128 edges per block
    edge_decoder_kernel<<<blocks, 256, 0, stream>>>(
        left, right, pairs, W1, b1, W2, b2, out, E);
}

// Round 2
// 147.995 us; speedup vs baseline: 1.1290x; 1.1290x over previous
//
#include <hip/hip_runtime.h>
#include <hip/hip_bf16.h>

typedef short bf16x8 __attribute__((ext_vector_type(8)));
typedef float f32x4  __attribute__((ext_vector_type(4)));

#define D  128
#define CH 16   // edges per wave-chunk (wave-private x staging, barrier-free)

// f32 -> bf16 round-to-nearest-even (finite inputs)
__device__ __forceinline__ short f2bf(float f) {
    unsigned u = __float_as_uint(f);
    u = (u + 0x7fffu + ((u >> 16) & 1u)) >> 16;
    return (short)u;
}

// LDS byte offset for [row][128 bf16], XOR-swizzled to kill the
// stride-256B bank conflict on ds_read_b128 column-slices (G4).
__device__ __forceinline__ int swz(int row, int intra) {
    return (row << 8) + (intra ^ ((row & 7) << 4));
}

// LDS: 32 KB W1^T + 4 waves * 4 KB x = 48 KB -> 3 blocks/CU (12 waves/CU)
__global__ __launch_bounds__(256, 3)
void edge_decoder_kernel(const float* __restrict__ left,
                         const float* __restrict__ right,
                         const int* __restrict__ pairs,
                         const float* __restrict__ W1,
                         const float* __restrict__ b1,
                         const float* __restrict__ W2,
                         const float* __restrict__ b2,
                         float* __restrict__ out, int E)
{
    __shared__ char smem[49152];
    char* const w1t = smem;                         // W1^T bf16, swizzled
    char* const xls = smem + 32768 + (threadIdx.x >> 6) * 4096; // wave-private

    const int tid  = threadIdx.x;
    const int lane = tid & 63;
    const int wid  = tid >> 6;
    const int lg   = lane >> 4;       // lanegroup 0..3
    const int lm   = lane & 15;
    const int half = lane >> 5;       // 0: pairs0 / even edges, 1: pairs1 / odd
    const int l32  = lane & 31;

    // ---- Phase 0: W1^T (bf16, transposed, swizzled) into LDS ----
    #pragma unroll 4
    for (int j = 0; j < 64; ++j) {
        int idx = j * 256 + tid;              // coalesced read of W1[k][c]
        int k = idx >> 7, c = idx & 127;
        *(short*)(w1t + swz(c, k * 2)) = f2bf(W1[idx]);
    }

    // per-lane slices of b1 / W2 (col = ct*16 + lm matches C-frag layout)
    float b1v[8], w2v[8];
    #pragma unroll
    for (int ct = 0; ct < 8; ++ct) {
        b1v[ct] = b1[ct * 16 + lm];
        w2v[ct] = W2[ct * 16 + lm];
    }
    const float b2s = b2[0];

    __syncthreads();                          // W1^T ready (only barrier)

    const int chunks = (E + CH - 1) / CH;
    const int stride = gridDim.x * 4;         // chunk-stride in wave units

    int c = blockIdx.x * 4 + wid;
    if (c >= chunks) return;

    // index layout per chunk: lanes 0-15 hold pairs0[base+lm],
    // lanes 32-47 hold pairs1[base+lm] (lanes 16-31/48-63 duplicate).
    auto load_idx = [&](int cc) {
        int e0 = cc * CH + lm;
        if (e0 >= E) e0 = E - 1;              // tail clamp: safe gather
        return pairs[half * E + e0];
    };

    int idxv = load_idx(c);

    while (true) {
        const int cn = c + stride;
        const int base = c * CH;
        // prefetch next chunk's indices; latency hides under MFMA/epilogue
        const int idxv_n = (cn < chunks) ? load_idx(cn) : 0;

        // ---- gather: issue ALL 16 row-loads before converting (ILP) ----
        float4 lv[8], rv[8];
        #pragma unroll
        for (int j = 0; j < 8; ++j) {
            const int eoff = 2 * j + half;    // 2 edges per j
            const int iL = __shfl(idxv, eoff);
            const int iR = __shfl(idxv, 32 + eoff);
            lv[j] = *(const float4*)(left  + iL * D + l32 * 4);
            rv[j] = *(const float4*)(right + iR * D + l32 * 4);
        }
        // ---- multiply + bf16 + transpose-stage to wave-private LDS ----
        #pragma unroll
        for (int j = 0; j < 8; ++j) {
            const int eoff = 2 * j + half;
            short4 xb;
            xb.x = f2bf(lv[j].x * rv[j].x);
            xb.y = f2bf(lv[j].y * rv[j].y);
            xb.z = f2bf(lv[j].z * rv[j].z);
            xb.w = f2bf(lv[j].w * rv[j].w);
            *(short4*)(xls + swz(eoff, l32 * 8)) = xb;
        }

        // ---- MFMA: A and B share the same k-mapping (K-perm invariant) ----
        bf16x8 afr[4];
        #pragma unroll
        for (int kt = 0; kt < 4; ++kt)
            afr[kt] = *(const bf16x8*)(xls + swz(lm, kt * 64 + lg * 16));

        f32x4 acc[8];
        #pragma unroll
        for (int ct = 0; ct < 8; ++ct) acc[ct] = (f32x4){0.f, 0.f, 0.f, 0.f};

        #pragma unroll
        for (int kt = 0; kt < 4; ++kt)
            #pragma unroll
            for (int ct = 0; ct < 8; ++ct) {
                const bf16x8 bfr = *(const bf16x8*)(
                    w1t + swz(ct * 16 + lm, kt * 64 + lg * 16));
                acc[ct] = __builtin_amdgcn_mfma_f32_16x16x32_bf16(
                    afr[kt], bfr, acc[ct], 0, 0, 0);
            }

        // ---- bias + ReLU + dot(W2) + 16-lane reduce + sigmoid ----
        // C-frag layout (HW-measured): col = lane&15, row = (lane>>4)*4 + reg.
        float p0 = 0.f, p1 = 0.f, p2 = 0.f, p3 = 0.f;
        #pragma unroll
        for (int ct = 0; ct < 8; ++ct) {
            float h0 = fmaxf(acc[ct][0] + b1v[ct], 0.f);
            float h1 = fmaxf(acc[ct][1] + b1v[ct], 0.f);
            float h2 = fmaxf(acc[ct][2] + b1v[ct], 0.f);
            float h3 = fmaxf(acc[ct][3] + b1v[ct], 0.f);
            p0 = fmaf(h0, w2v[ct], p0);
            p1 = fmaf(h1, w2v[ct], p1);
            p2 = fmaf(h2, w2v[ct], p2);
            p3 = fmaf(h3, w2v[ct], p3);
        }
        #pragma unroll
        for (int s = 1; s < 16; s <<= 1) {
            p0 += __shfl_xor(p0, s);
            p1 += __shfl_xor(p1, s);
            p2 += __shfl_xor(p2, s);
            p3 += __shfl_xor(p3, s);
        }
        if (lm < 4) {
            const float pv = (lm & 2) ? ((lm & 1) ? p3 : p2)
                                      : ((lm & 1) ? p1 : p0);
            const int e = base + lg * 4 + lm;   // row = lg*4 + reg
            if (e < E) out[e] = 1.f / (1.f + __expf(-(pv + b2s)));
        }

        if (cn >= chunks) break;
        c = cn;
        idxv = idxv_n;
    }
}

extern "C" void kernel_launch(void* const* d_in, const int* in_sizes, int n_in,
                              void* d_out, int out_size, void* d_ws, size_t ws_size,
                              hipStream_t stream) {
    const float* left  = (const float*)d_in[0];
    const float* right = (const float*)d_in[1];
    const int*   pairs = (const int*)d_in[2];
    const float* W1    = (const float*)d_in[3];
    const float* b1    = (const float*)d_in[4];
    const float* W2    = (const float*)d_in[5];
    const float* b2    = (const float*)d_in[6];
    float* out = (float*)d_out;

    const int E = in_sizes[2] / 2;                 // pairs is [2][E]
    const int chunks = (E + CH - 1) / CH;
    int blocks = 768;                              // 3 blocks/CU * 256 CU
    const int need = (chunks + 3) / 4;             // 4 wave-chunks per block
    if (need < blocks) blocks = need;
    edge_decoder_kernel<<<blocks, 256, 0, stream>>>(
        left, right, pairs, W1, b1, W2, b2, out, E);
}